// Round 18
// baseline (45.010 us; speedup 1.0000x reference)
//
#include <hip/hip_runtime.h>
#include <cstddef>

#define BB 32
#define NN 2000
#define EE 128
#define HH 8
#define DD 16
#define NCH 32
#define CHN 64
#define NEGV (-1e9f)

typedef __attribute__((ext_vector_type(8))) short short8v;
typedef __attribute__((ext_vector_type(4))) float f32x4;

__device__ __forceinline__ short f2bf(float f) {
  unsigned u = __float_as_uint(f);
  unsigned r = (u + 0x7FFFu + ((u >> 16) & 1u)) >> 16;
  return (short)r;
}
__device__ __forceinline__ float bf2f(short s) {
  return __uint_as_float(((unsigned)(unsigned short)s) << 16);
}

// ws layout (bytes):
// pctx_bf [B][NCH][H][E] u16 @ 0         2097152
// pm      [B][NCH][H] f32   @ 2097152      32768
// ps      [B][NCH][H] f32   @ 2129920      32768

// K1: quad-split vectorized qproj + 2-chunk MFMA flash, async-staged ne.
// grid (16, BB) = 512 blocks, 256 thr.
__global__ __launch_bounds__(256) void k_fused(
    const float* __restrict__ ds, const float* __restrict__ ne, const int* __restrict__ mask,
    const float* __restrict__ Wq, const float* __restrict__ bq,
    const float* __restrict__ Wk, const float* __restrict__ bk,
    short* __restrict__ pctx, float* __restrict__ pm, float* __restrict__ ps) {
  const int cpair = blockIdx.x, b = blockIdx.y, t = threadIdx.x;

  __shared__ float ds_s[EE], q_s[EE];
  __shared__ __align__(16) float4 part4q[256];   // [eh 0..7][oq 0..31]
  __shared__ __align__(16) short qk_sub[16 * EE];
  __shared__ float qbk_s[HH];
  __shared__ __align__(16) short ne_sub[CHN * EE];
  __shared__ __align__(16) short wT[16 * 72];
  __shared__ float att_s[HH * 66];
  __shared__ int mask_s[CHN];

  const int baseA = (2 * cpair) * CHN;
  const int baseB = baseA + CHN;
  const int cntB = (NN - baseB < CHN) ? (NN - baseB) : CHN;
  const int nrow = t >> 4, oct = t & 15;

  float4 pA[8];
#pragma unroll
  for (int i = 0; i < 4; ++i) {
    const int n = i * 16 + nrow;
    const float4* sA = (const float4*)(ne + ((size_t)b * NN + baseA + n) * EE + oct * 8);
    pA[2 * i] = sA[0]; pA[2 * i + 1] = sA[1];
  }
  int maskA_r = 0;
  if (t < CHN) maskA_r = mask[b * NN + baseA + t];
  if (t < EE) ds_s[t] = ds[b * EE + t];
  __builtin_amdgcn_sched_barrier(0);
  __syncthreads();

  // ---- qproj: quad-split vectorized. thread = (oq 0..31, eh 0..7) ----
  const int oq = t & 31, eh = t >> 5;
  {
    float4 a4 = {0.f, 0.f, 0.f, 0.f};
#pragma unroll 4
    for (int e = eh * 16; e < eh * 16 + 16; ++e) {
      const float4 wv = *(const float4*)(Wq + e * EE + oq * 4);
      const float xx = ds_s[e];
      a4.x = fmaf(xx, wv.x, a4.x); a4.y = fmaf(xx, wv.y, a4.y);
      a4.z = fmaf(xx, wv.z, a4.z); a4.w = fmaf(xx, wv.w, a4.w);
    }
    part4q[eh * 32 + oq] = a4;
  }
  __syncthreads();
  if (t < 128) {
    float s = 0.f;
#pragma unroll
    for (int e8 = 0; e8 < 8; ++e8) s += ((const float*)&part4q[e8 * 32 + (t >> 2)])[t & 3];
    q_s[t] = bq[t] + s;
  }
  __syncthreads();

  // ---- qkh[h][e] = sum_d Wk[e][h*16+d] * q[h*16+d], all 256 threads ----
#pragma unroll
  for (int k = 0; k < 4; ++k) {
    const int f = t + k * 256;
    const int h = f >> 7, e = f & 127;
    const float4* wk4 = (const float4*)(Wk + e * EE + h * DD);
    const float4* q4 = (const float4*)(q_s + h * DD);
    float s = 0.f;
#pragma unroll
    for (int i = 0; i < 4; ++i) {
      const float4 w = wk4[i], q = q4[i];
      s += w.x * q.x + w.y * q.y + w.z * q.z + w.w * q.w;
    }
    qk_sub[((e >> 4) * 4 + (h >> 2)) * 64 + (h & 3) * 16 + (e & 15)] = f2bf(s);
  }
  for (int f = t; f < 512; f += 256) {
    const int eb = f >> 6, r = f & 63;
    ((int*)(qk_sub + eb * 256 + 128))[r] = 0;
  }
  if (t < HH) {
    float s = 0.f;
#pragma unroll
    for (int d = 0; d < DD; ++d) s += q_s[t * DD + d] * bk[t * DD + d];
    qbk_s[t] = s;
  }
  for (int f = t; f < 288; f += 256) ((int*)(wT + 8 * 72))[f] = 0;

  if (t < CHN) mask_s[t] = maskA_r;
#pragma unroll
  for (int i = 0; i < 4; ++i) {
    const int n = i * 16 + nrow;
    short8v s8;
    s8[0] = f2bf(pA[2 * i].x);     s8[1] = f2bf(pA[2 * i].y);
    s8[2] = f2bf(pA[2 * i].z);     s8[3] = f2bf(pA[2 * i].w);
    s8[4] = f2bf(pA[2 * i + 1].x); s8[5] = f2bf(pA[2 * i + 1].y);
    s8[6] = f2bf(pA[2 * i + 1].z); s8[7] = f2bf(pA[2 * i + 1].w);
    *(short8v*)(ne_sub + ((oct >> 1) * 16 + (n >> 2)) * 64 + (n & 3) * 16 + (oct & 1) * 8) = s8;
  }

  float4 pB[8];
#pragma unroll
  for (int i = 0; i < 4; ++i) {
    const int n = i * 16 + nrow;
    if (n < cntB) {
      const float4* sB = (const float4*)(ne + ((size_t)b * NN + baseB + n) * EE + oct * 8);
      pB[2 * i] = sB[0]; pB[2 * i + 1] = sB[1];
    } else {
      pB[2 * i] = make_float4(0.f, 0.f, 0.f, 0.f);
      pB[2 * i + 1] = make_float4(0.f, 0.f, 0.f, 0.f);
    }
  }
  int maskB_r = 0;
  if (t < CHN) maskB_r = (t < cntB) ? mask[b * NN + baseB + t] : 0;
  __builtin_amdgcn_sched_barrier(0);
  __syncthreads();

  const int w = t >> 6;
  const int l = t & 63;
  const int g = l >> 4;
  const int l15 = l & 15;

#pragma unroll 1
  for (int cc = 0; cc < 2; ++cc) {
    const int ci = 2 * cpair + cc;

    {
      f32x4 qacc = {0.f, 0.f, 0.f, 0.f};
      const int rn = w * 16 + l15;
#pragma unroll
      for (int ks = 0; ks < 4; ++ks) {
        const int eb = ks * 2 + (g >> 1), elo = (g & 1) * 8;
        short8v a = *(const short8v*)(qk_sub + (eb * 4 + (l15 >> 2)) * 64 + (l15 & 3) * 16 + elo);
        short8v bb = *(const short8v*)(ne_sub + (eb * 16 + (rn >> 2)) * 64 + (rn & 3) * 16 + elo);
        qacc = __builtin_amdgcn_mfma_f32_16x16x32_bf16(a, bb, qacc, 0, 0, 0);
      }
      if (g < 2) {
#pragma unroll
        for (int r = 0; r < 4; ++r) {
          const int h = g * 4 + r;
          att_s[h * 66 + rn] = mask_s[rn] ? (qacc[r] + qbk_s[h]) * 0.25f : NEGV;
        }
      }
    }
    __syncthreads();

    {
      const int h = t >> 5, l32 = t & 31;
      const float a0 = att_s[h * 66 + l32], a1 = att_s[h * 66 + l32 + 32];
      float mx = fmaxf(a0, a1);
#pragma unroll
      for (int k = 16; k >= 1; k >>= 1) mx = fmaxf(mx, __shfl_xor(mx, k, 32));
      const float w0 = mask_s[l32] ? expf(a0 - mx) : 0.f;
      const float w1 = mask_s[l32 + 32] ? expf(a1 - mx) : 0.f;
      const short s0 = f2bf(w0), s1 = f2bf(w1);
      float sm = bf2f(s0) + bf2f(s1);
#pragma unroll
      for (int k = 16; k >= 1; k >>= 1) sm += __shfl_xor(sm, k, 32);
      wT[h * 72 + l32] = s0;
      wT[h * 72 + l32 + 32] = s1;
      if (l32 == 0) {
        pm[(b * NCH + ci) * HH + h] = mx;
        ps[(b * NCH + ci) * HH + h] = sm;
      }
    }
    __syncthreads();

    {
      f32x4 pacc0 = {0.f, 0.f, 0.f, 0.f}, pacc1 = {0.f, 0.f, 0.f, 0.f};
#pragma unroll
      for (int ks = 0; ks < 2; ++ks) {
        short8v a = *(const short8v*)(wT + l15 * 72 + ks * 32 + g * 8);
#pragma unroll
        for (int ti = 0; ti < 2; ++ti) {
          const int e = (2 * w + ti) * 16 + l15;
          short8v bb;
#pragma unroll
          for (int j = 0; j < 8; ++j) {
            const int n = ks * 32 + g * 8 + j;
            bb[j] = ne_sub[((e >> 4) * 16 + (n >> 2)) * 64 + (n & 3) * 16 + (e & 15)];
          }
          if (ti == 0) pacc0 = __builtin_amdgcn_mfma_f32_16x16x32_bf16(a, bb, pacc0, 0, 0, 0);
          else         pacc1 = __builtin_amdgcn_mfma_f32_16x16x32_bf16(a, bb, pacc1, 0, 0, 0);
        }
      }
      if (g < 2) {
        short* dst = pctx + ((size_t)(b * NCH + ci) * HH) * EE;
#pragma unroll
        for (int r = 0; r < 4; ++r) {
          const int h = g * 4 + r;
          dst[h * EE + (2 * w) * 16 + l15]     = f2bf(pacc0[r]);
          dst[h * EE + (2 * w + 1) * 16 + l15] = f2bf(pacc1[r]);
        }
      }
    }

    if (cc == 0) {
      __syncthreads();
      if (t < CHN) mask_s[t] = maskB_r;
#pragma unroll
      for (int i = 0; i < 4; ++i) {
        const int n = i * 16 + nrow;
        short8v s8;
        s8[0] = f2bf(pB[2 * i].x);     s8[1] = f2bf(pB[2 * i].y);
        s8[2] = f2bf(pB[2 * i].z);     s8[3] = f2bf(pB[2 * i].w);
        s8[4] = f2bf(pB[2 * i + 1].x); s8[5] = f2bf(pB[2 * i + 1].y);
        s8[6] = f2bf(pB[2 * i + 1].z); s8[7] = f2bf(pB[2 * i + 1].w);
        *(short8v*)(ne_sub + ((oct >> 1) * 16 + (n >> 2)) * 64 + (n & 3) * 16 + (oct & 1) * 8) = s8;
      }
      __syncthreads();
    }
  }
}

// K2 (R17-verified, 44.5): vectorized merge + quad-split matvecs + prefetch + scores.
// grid (16, BB), 256 thr.
__global__ __launch_bounds__(256) void k_head_scores(
    const float* __restrict__ ne,
    const short* __restrict__ pctx, const float* __restrict__ pm, const float* __restrict__ ps,
    const float* __restrict__ Wv, const float* __restrict__ bv,
    const float* __restrict__ Wo, const float* __restrict__ bo,
    const float* __restrict__ Wp, const float* __restrict__ bp,
    const float* __restrict__ ln_g, const float* __restrict__ ln_b,
    const int* __restrict__ visited, const int* __restrict__ prev_node,
    const int* __restrict__ all_visited, const float* __restrict__ ew,
    const float* __restrict__ sb_p, const float* __restrict__ rp_p,
    float* __restrict__ out) {
  const int x = blockIdx.x, b = blockIdx.y, t = threadIdx.x;
  __shared__ float mg_s[HH], dn_s[HH];
  __shared__ float sc_s[NCH * HH];
  __shared__ float part[2][HH * EE];
  __shared__ float cE[HH * EE];
  __shared__ __align__(16) float4 part4[256];   // [eh 0..7][oq 0..31]
  __shared__ float buf[EE];
  __shared__ float ctxo[EE];
  __shared__ float red[128];
  __shared__ float lg_s[EE];

  const int g = t >> 5, l = t & 31;
  const int nb = x * 125;
  float4 pref[16];
#pragma unroll
  for (int i = 0; i < 16; ++i) {
    const int nl = i * 8 + g;
    const int n = nb + ((nl < 125) ? nl : 0);
    pref[i] = *(const float4*)(ne + ((size_t)b * NN + n) * EE + l * 4);
  }
  __builtin_amdgcn_sched_barrier(0);

  if (t < HH) {
    float m = -INFINITY;
    for (int c = 0; c < NCH; ++c) m = fmaxf(m, pm[(b * NCH + c) * HH + t]);
    float dn = 0.f;
    for (int c = 0; c < NCH; ++c) dn += expf(pm[(b * NCH + c) * HH + t] - m) * ps[(b * NCH + c) * HH + t];
    mg_s[t] = m; dn_s[t] = dn;
  }
  __syncthreads();
  {
    const int c = t >> 3, hh = t & 7;
    sc_s[t] = expf(pm[(b * NCH + c) * HH + hh] - mg_s[hh]) / dn_s[hh];
  }
  __syncthreads();

  {
    const int grp = t >> 1;
    const int hh = grp >> 4, e0 = (grp & 15) * 8;
    const int c0 = (t & 1) * 16;
    float a8[8] = {0.f, 0.f, 0.f, 0.f, 0.f, 0.f, 0.f, 0.f};
#pragma unroll 4
    for (int c = c0; c < c0 + 16; ++c) {
      const short8v v = *(const short8v*)(pctx + ((size_t)(b * NCH + c) * HH + hh) * EE + e0);
      const float sc = sc_s[c * HH + hh];
#pragma unroll
      for (int j = 0; j < 8; ++j) a8[j] = fmaf(sc, bf2f(v[j]), a8[j]);
    }
#pragma unroll
    for (int j = 0; j < 8; ++j) part[t & 1][hh * EE + e0 + j] = a8[j];
  }
  __syncthreads();
  for (int f = t; f < HH * EE; f += 256) cE[f] = part[0][f] + part[1][f];
  __syncthreads();

  const int oq = t & 31, eh = t >> 5;
  {
    const float* xv = cE + (oq >> 2) * EE;
    float4 a4 = {0.f, 0.f, 0.f, 0.f};
#pragma unroll 4
    for (int e = eh * 16; e < eh * 16 + 16; ++e) {
      const float4 wv = *(const float4*)(Wv + e * EE + oq * 4);
      const float xx = xv[e];
      a4.x = fmaf(xx, wv.x, a4.x); a4.y = fmaf(xx, wv.y, a4.y);
      a4.z = fmaf(xx, wv.z, a4.z); a4.w = fmaf(xx, wv.w, a4.w);
    }
    part4[eh * 32 + oq] = a4;
  }
  __syncthreads();
  if (t < 128) {
    float s = 0.f;
#pragma unroll
    for (int e8 = 0; e8 < 8; ++e8) s += ((const float*)&part4[e8 * 32 + (t >> 2)])[t & 3];
    buf[t] = bv[t] + s;
  }
  __syncthreads();

  {
    float4 a4 = {0.f, 0.f, 0.f, 0.f};
#pragma unroll 4
    for (int e = eh * 16; e < eh * 16 + 16; ++e) {
      const float4 wv = *(const float4*)(Wo + e * EE + oq * 4);
      const float xx = buf[e];
      a4.x = fmaf(xx, wv.x, a4.x); a4.y = fmaf(xx, wv.y, a4.y);
      a4.z = fmaf(xx, wv.z, a4.z); a4.w = fmaf(xx, wv.w, a4.w);
    }
    part4[eh * 32 + oq] = a4;
  }
  __syncthreads();
  if (t < 128) {
    float s = 0.f;
#pragma unroll
    for (int e8 = 0; e8 < 8; ++e8) s += ((const float*)&part4[e8 * 32 + (t >> 2)])[t & 3];
    ctxo[t] = bo[t] + s;
  }
  __syncthreads();

  if (t < 128) red[t] = ctxo[t];
  __syncthreads();
  for (int s = 64; s > 0; s >>= 1) { if (t < s) red[t] += red[t + s]; __syncthreads(); }
  const float mu = red[0] / EE;
  __syncthreads();
  if (t < 128) red[t] = (ctxo[t] - mu) * (ctxo[t] - mu);
  __syncthreads();
  for (int s = 64; s > 0; s >>= 1) { if (t < s) red[t] += red[t + s]; __syncthreads(); }
  const float rstd = rsqrtf(red[0] / EE + 1e-5f);
  __syncthreads();
  if (t < 128) buf[t] = (ctxo[t] - mu) * rstd * ln_g[t] + ln_b[t];
  __syncthreads();

  {
    float4 a4 = {0.f, 0.f, 0.f, 0.f};
#pragma unroll 4
    for (int e = eh * 16; e < eh * 16 + 16; ++e) {
      const float4 wv = *(const float4*)(Wp + e * EE + oq * 4);
      const float xx = buf[e];
      a4.x = fmaf(xx, wv.x, a4.x); a4.y = fmaf(xx, wv.y, a4.y);
      a4.z = fmaf(xx, wv.z, a4.z); a4.w = fmaf(xx, wv.w, a4.w);
    }
    part4[eh * 32 + oq] = a4;
  }
  __syncthreads();
  if (t < 128) {
    float s = 0.f;
#pragma unroll
    for (int e8 = 0; e8 < 8; ++e8) s += ((const float*)&part4[e8 * 32 + (t >> 2)])[t & 3];
    lg_s[t] = bp[t] + s;
  }
  __syncthreads();

  const float4 lg = *(const float4*)(lg_s + l * 4);
  const bool av = all_visited[b] != 0;
  const int pv = prev_node[b];
  const float direct = av ? ew[((size_t)b * NN + pv) * NN] : 1.f;
  const float sbv = sb_p[0], rpv = rp_p[0];
#pragma unroll
  for (int i = 0; i < 16; ++i) {
    const int nl = i * 8 + g;
    if (nl < 125) {
      const int n = nb + nl;
      const float4 a = pref[i];
      float d = a.x * lg.x + a.y * lg.y + a.z * lg.z + a.w * lg.w;
#pragma unroll
      for (int k = 16; k >= 1; k >>= 1) d += __shfl_xor(d, k, 32);
      if (l == 0) {
        float sc = d;
        if (!av) {
          if (visited[b * NN + n] != 0) sc = rpv;
        } else {
          const float via = ew[((size_t)b * NN + pv) * NN + n] + ew[((size_t)b * NN + n) * NN];
          if (via < direct) sc += sbv * (direct - via) / direct;
        }
        out[b * NN + n] = sc;
      }
    }
  }
}

extern "C" void kernel_launch(void* const* d_in, const int* in_sizes, int n_in,
                              void* d_out, int out_size, void* d_ws, size_t ws_size,
                              hipStream_t stream) {
  const float* ds   = (const float*)d_in[0];
  const float* ne   = (const float*)d_in[1];
  const int*   mask = (const int*)d_in[2];
  const float* ew   = (const float*)d_in[3];
  const int*   visited = (const int*)d_in[4];
  const int*   prev = (const int*)d_in[5];
  const int*   allv = (const int*)d_in[6];
  const float* Wq = (const float*)d_in[7];
  const float* bq = (const float*)d_in[8];
  const float* Wk = (const float*)d_in[9];
  const float* bk = (const float*)d_in[10];
  const float* Wv = (const float*)d_in[11];
  const float* bv = (const float*)d_in[12];
  const float* Wo = (const float*)d_in[13];
  const float* bo = (const float*)d_in[14];
  const float* Wp = (const float*)d_in[15];
  const float* bp = (const float*)d_in[16];
  const float* ln_g = (const float*)d_in[17];
  const float* ln_b = (const float*)d_in[18];
  const float* sb = (const float*)d_in[19];
  const float* rp = (const float*)d_in[20];
  float* out = (float*)d_out;
  char* ws = (char*)d_ws;

  short* pctx = (short*)ws;
  float* pm   = (float*)(ws + 2097152);
  float* ps   = (float*)(ws + 2129920);

  k_fused<<<dim3(16, BB), 256, 0, stream>>>(ds, ne, mask, Wq, bq, Wk, bk, pctx, pm, ps);
  k_head_scores<<<dim3(16, BB), 256, 0, stream>>>(ne, pctx, pm, ps, Wv, bv, Wo, bo, Wp, bp,
                                                  ln_g, ln_b, visited, prev, allv, ew, sb, rp, out);
}

// Round 19
// 44.242 us; speedup vs baseline: 1.0174x; 1.0174x over previous
//
#include <hip/hip_runtime.h>
#include <cstddef>

#define BB 32
#define NN 2000
#define EE 128
#define HH 8
#define DD 16
#define NCH 32
#define CHN 64
#define NEGV (-1e9f)

typedef __attribute__((ext_vector_type(8))) short short8v;
typedef __attribute__((ext_vector_type(4))) float f32x4;

__device__ __forceinline__ short f2bf(float f) {
  unsigned u = __float_as_uint(f);
  unsigned r = (u + 0x7FFFu + ((u >> 16) & 1u)) >> 16;
  return (short)r;
}
__device__ __forceinline__ float bf2f(short s) {
  return __uint_as_float(((unsigned)(unsigned short)s) << 16);
}

// ws layout (bytes):
// pctx_bf [B][NCH][H][E] u16 @ 0         2097152
// pm      [B][NCH][H] f32   @ 2097152      32768
// ps      [B][NCH][H] f32   @ 2129920      32768

// K1 (R14/R17-verified, 44.5): split-K qproj + 2-chunk MFMA flash, async-staged ne.
// grid (16, BB) = 512 blocks, 256 thr.
__global__ __launch_bounds__(256) void k_fused(
    const float* __restrict__ ds, const float* __restrict__ ne, const int* __restrict__ mask,
    const float* __restrict__ Wq, const float* __restrict__ bq,
    const float* __restrict__ Wk, const float* __restrict__ bk,
    short* __restrict__ pctx, float* __restrict__ pm, float* __restrict__ ps) {
  const int cpair = blockIdx.x, b = blockIdx.y, t = threadIdx.x;

  __shared__ float ds_s[EE], q_s[EE];
  __shared__ float redq[256];
  __shared__ __align__(16) short qk_sub[16 * EE];
  __shared__ float qbk_s[HH];
  __shared__ __align__(16) short ne_sub[CHN * EE];
  __shared__ __align__(16) short wT[16 * 72];
  __shared__ float att_s[HH * 66];
  __shared__ int mask_s[CHN];

  const int baseA = (2 * cpair) * CHN;
  const int baseB = baseA + CHN;
  const int cntB = (NN - baseB < CHN) ? (NN - baseB) : CHN;
  const int nrow = t >> 4, oct = t & 15;

  float4 pA[8];
#pragma unroll
  for (int i = 0; i < 4; ++i) {
    const int n = i * 16 + nrow;
    const float4* sA = (const float4*)(ne + ((size_t)b * NN + baseA + n) * EE + oct * 8);
    pA[2 * i] = sA[0]; pA[2 * i + 1] = sA[1];
  }
  int maskA_r = 0;
  if (t < CHN) maskA_r = mask[b * NN + baseA + t];
  if (t < EE) ds_s[t] = ds[b * EE + t];
  __builtin_amdgcn_sched_barrier(0);
  __syncthreads();

  const int o = t & 127, half = t >> 7;
  {
    const int c0 = half * 64;
    float a0 = 0.f, a1 = 0.f, a2 = 0.f, a3 = 0.f;
    for (int c = c0; c < c0 + 64; c += 4) {
      a0 = fmaf(ds_s[c],     Wq[(c)     * EE + o], a0);
      a1 = fmaf(ds_s[c + 1], Wq[(c + 1) * EE + o], a1);
      a2 = fmaf(ds_s[c + 2], Wq[(c + 2) * EE + o], a2);
      a3 = fmaf(ds_s[c + 3], Wq[(c + 3) * EE + o], a3);
    }
    redq[t] = (a0 + a1) + (a2 + a3);
  }
  __syncthreads();
  if (t < 128) q_s[t] = bq[t] + redq[t] + redq[t + 128];
  __syncthreads();

#pragma unroll
  for (int k = 0; k < 4; ++k) {
    const int f = t + k * 256;
    const int h = f >> 7, e = f & 127;
    const float4* wk4 = (const float4*)(Wk + e * EE + h * DD);
    const float4* q4 = (const float4*)(q_s + h * DD);
    float s = 0.f;
#pragma unroll
    for (int i = 0; i < 4; ++i) {
      const float4 w = wk4[i], q = q4[i];
      s += w.x * q.x + w.y * q.y + w.z * q.z + w.w * q.w;
    }
    qk_sub[((e >> 4) * 4 + (h >> 2)) * 64 + (h & 3) * 16 + (e & 15)] = f2bf(s);
  }
  for (int f = t; f < 512; f += 256) {
    const int eb = f >> 6, r = f & 63;
    ((int*)(qk_sub + eb * 256 + 128))[r] = 0;
  }
  if (t < HH) {
    float s = 0.f;
#pragma unroll
    for (int d = 0; d < DD; ++d) s += q_s[t * DD + d] * bk[t * DD + d];
    qbk_s[t] = s;
  }
  for (int f = t; f < 288; f += 256) ((int*)(wT + 8 * 72))[f] = 0;

  if (t < CHN) mask_s[t] = maskA_r;
#pragma unroll
  for (int i = 0; i < 4; ++i) {
    const int n = i * 16 + nrow;
    short8v s8;
    s8[0] = f2bf(pA[2 * i].x);     s8[1] = f2bf(pA[2 * i].y);
    s8[2] = f2bf(pA[2 * i].z);     s8[3] = f2bf(pA[2 * i].w);
    s8[4] = f2bf(pA[2 * i + 1].x); s8[5] = f2bf(pA[2 * i + 1].y);
    s8[6] = f2bf(pA[2 * i + 1].z); s8[7] = f2bf(pA[2 * i + 1].w);
    *(short8v*)(ne_sub + ((oct >> 1) * 16 + (n >> 2)) * 64 + (n & 3) * 16 + (oct & 1) * 8) = s8;
  }

  float4 pB[8];
#pragma unroll
  for (int i = 0; i < 4; ++i) {
    const int n = i * 16 + nrow;
    if (n < cntB) {
      const float4* sB = (const float4*)(ne + ((size_t)b * NN + baseB + n) * EE + oct * 8);
      pB[2 * i] = sB[0]; pB[2 * i + 1] = sB[1];
    } else {
      pB[2 * i] = make_float4(0.f, 0.f, 0.f, 0.f);
      pB[2 * i + 1] = make_float4(0.f, 0.f, 0.f, 0.f);
    }
  }
  int maskB_r = 0;
  if (t < CHN) maskB_r = (t < cntB) ? mask[b * NN + baseB + t] : 0;
  __builtin_amdgcn_sched_barrier(0);
  __syncthreads();

  const int w = t >> 6;
  const int l = t & 63;
  const int g = l >> 4;
  const int l15 = l & 15;

#pragma unroll 1
  for (int cc = 0; cc < 2; ++cc) {
    const int ci = 2 * cpair + cc;

    {
      f32x4 qacc = {0.f, 0.f, 0.f, 0.f};
      const int rn = w * 16 + l15;
#pragma unroll
      for (int ks = 0; ks < 4; ++ks) {
        const int eb = ks * 2 + (g >> 1), elo = (g & 1) * 8;
        short8v a = *(const short8v*)(qk_sub + (eb * 4 + (l15 >> 2)) * 64 + (l15 & 3) * 16 + elo);
        short8v bb = *(const short8v*)(ne_sub + (eb * 16 + (rn >> 2)) * 64 + (rn & 3) * 16 + elo);
        qacc = __builtin_amdgcn_mfma_f32_16x16x32_bf16(a, bb, qacc, 0, 0, 0);
      }
      if (g < 2) {
#pragma unroll
        for (int r = 0; r < 4; ++r) {
          const int h = g * 4 + r;
          att_s[h * 66 + rn] = mask_s[rn] ? (qacc[r] + qbk_s[h]) * 0.25f : NEGV;
        }
      }
    }
    __syncthreads();

    {
      const int h = t >> 5, l32 = t & 31;
      const float a0 = att_s[h * 66 + l32], a1 = att_s[h * 66 + l32 + 32];
      float mx = fmaxf(a0, a1);
#pragma unroll
      for (int k = 16; k >= 1; k >>= 1) mx = fmaxf(mx, __shfl_xor(mx, k, 32));
      const float w0 = mask_s[l32] ? expf(a0 - mx) : 0.f;
      const float w1 = mask_s[l32 + 32] ? expf(a1 - mx) : 0.f;
      const short s0 = f2bf(w0), s1 = f2bf(w1);
      float sm = bf2f(s0) + bf2f(s1);
#pragma unroll
      for (int k = 16; k >= 1; k >>= 1) sm += __shfl_xor(sm, k, 32);
      wT[h * 72 + l32] = s0;
      wT[h * 72 + l32 + 32] = s1;
      if (l32 == 0) {
        pm[(b * NCH + ci) * HH + h] = mx;
        ps[(b * NCH + ci) * HH + h] = sm;
      }
    }
    __syncthreads();

    {
      f32x4 pacc0 = {0.f, 0.f, 0.f, 0.f}, pacc1 = {0.f, 0.f, 0.f, 0.f};
#pragma unroll
      for (int ks = 0; ks < 2; ++ks) {
        short8v a = *(const short8v*)(wT + l15 * 72 + ks * 32 + g * 8);
#pragma unroll
        for (int ti = 0; ti < 2; ++ti) {
          const int e = (2 * w + ti) * 16 + l15;
          short8v bb;
#pragma unroll
          for (int j = 0; j < 8; ++j) {
            const int n = ks * 32 + g * 8 + j;
            bb[j] = ne_sub[((e >> 4) * 16 + (n >> 2)) * 64 + (n & 3) * 16 + (e & 15)];
          }
          if (ti == 0) pacc0 = __builtin_amdgcn_mfma_f32_16x16x32_bf16(a, bb, pacc0, 0, 0, 0);
          else         pacc1 = __builtin_amdgcn_mfma_f32_16x16x32_bf16(a, bb, pacc1, 0, 0, 0);
        }
      }
      if (g < 2) {
        short* dst = pctx + ((size_t)(b * NCH + ci) * HH) * EE;
#pragma unroll
        for (int r = 0; r < 4; ++r) {
          const int h = g * 4 + r;
          dst[h * EE + (2 * w) * 16 + l15]     = f2bf(pacc0[r]);
          dst[h * EE + (2 * w + 1) * 16 + l15] = f2bf(pacc1[r]);
        }
      }
    }

    if (cc == 0) {
      __syncthreads();
      if (t < CHN) mask_s[t] = maskB_r;
#pragma unroll
      for (int i = 0; i < 4; ++i) {
        const int n = i * 16 + nrow;
        short8v s8;
        s8[0] = f2bf(pB[2 * i].x);     s8[1] = f2bf(pB[2 * i].y);
        s8[2] = f2bf(pB[2 * i].z);     s8[3] = f2bf(pB[2 * i].w);
        s8[4] = f2bf(pB[2 * i + 1].x); s8[5] = f2bf(pB[2 * i + 1].y);
        s8[6] = f2bf(pB[2 * i + 1].z); s8[7] = f2bf(pB[2 * i + 1].w);
        *(short8v*)(ne_sub + ((oct >> 1) * 16 + (n >> 2)) * 64 + (n & 3) * 16 + (oct & 1) * 8) = s8;
      }
      __syncthreads();
    }
  }
}

// K2 (R17-verified, 44.5): vectorized merge + quad-split matvecs + prefetch + scores.
// grid (16, BB), 256 thr.
__global__ __launch_bounds__(256) void k_head_scores(
    const float* __restrict__ ne,
    const short* __restrict__ pctx, const float* __restrict__ pm, const float* __restrict__ ps,
    const float* __restrict__ Wv, const float* __restrict__ bv,
    const float* __restrict__ Wo, const float* __restrict__ bo,
    const float* __restrict__ Wp, const float* __restrict__ bp,
    const float* __restrict__ ln_g, const float* __restrict__ ln_b,
    const int* __restrict__ visited, const int* __restrict__ prev_node,
    const int* __restrict__ all_visited, const float* __restrict__ ew,
    const float* __restrict__ sb_p, const float* __restrict__ rp_p,
    float* __restrict__ out) {
  const int x = blockIdx.x, b = blockIdx.y, t = threadIdx.x;
  __shared__ float mg_s[HH], dn_s[HH];
  __shared__ float sc_s[NCH * HH];
  __shared__ float part[2][HH * EE];
  __shared__ float cE[HH * EE];
  __shared__ __align__(16) float4 part4[256];   // [eh 0..7][oq 0..31]
  __shared__ float buf[EE];
  __shared__ float ctxo[EE];
  __shared__ float red[128];
  __shared__ float lg_s[EE];

  const int g = t >> 5, l = t & 31;
  const int nb = x * 125;
  float4 pref[16];
#pragma unroll
  for (int i = 0; i < 16; ++i) {
    const int nl = i * 8 + g;
    const int n = nb + ((nl < 125) ? nl : 0);
    pref[i] = *(const float4*)(ne + ((size_t)b * NN + n) * EE + l * 4);
  }
  __builtin_amdgcn_sched_barrier(0);

  if (t < HH) {
    float m = -INFINITY;
    for (int c = 0; c < NCH; ++c) m = fmaxf(m, pm[(b * NCH + c) * HH + t]);
    float dn = 0.f;
    for (int c = 0; c < NCH; ++c) dn += expf(pm[(b * NCH + c) * HH + t] - m) * ps[(b * NCH + c) * HH + t];
    mg_s[t] = m; dn_s[t] = dn;
  }
  __syncthreads();
  {
    const int c = t >> 3, hh = t & 7;
    sc_s[t] = expf(pm[(b * NCH + c) * HH + hh] - mg_s[hh]) / dn_s[hh];
  }
  __syncthreads();

  {
    const int grp = t >> 1;
    const int hh = grp >> 4, e0 = (grp & 15) * 8;
    const int c0 = (t & 1) * 16;
    float a8[8] = {0.f, 0.f, 0.f, 0.f, 0.f, 0.f, 0.f, 0.f};
#pragma unroll 4
    for (int c = c0; c < c0 + 16; ++c) {
      const short8v v = *(const short8v*)(pctx + ((size_t)(b * NCH + c) * HH + hh) * EE + e0);
      const float sc = sc_s[c * HH + hh];
#pragma unroll
      for (int j = 0; j < 8; ++j) a8[j] = fmaf(sc, bf2f(v[j]), a8[j]);
    }
#pragma unroll
    for (int j = 0; j < 8; ++j) part[t & 1][hh * EE + e0 + j] = a8[j];
  }
  __syncthreads();
  for (int f = t; f < HH * EE; f += 256) cE[f] = part[0][f] + part[1][f];
  __syncthreads();

  const int oq = t & 31, eh = t >> 5;
  {
    const float* xv = cE + (oq >> 2) * EE;
    float4 a4 = {0.f, 0.f, 0.f, 0.f};
#pragma unroll 4
    for (int e = eh * 16; e < eh * 16 + 16; ++e) {
      const float4 wv = *(const float4*)(Wv + e * EE + oq * 4);
      const float xx = xv[e];
      a4.x = fmaf(xx, wv.x, a4.x); a4.y = fmaf(xx, wv.y, a4.y);
      a4.z = fmaf(xx, wv.z, a4.z); a4.w = fmaf(xx, wv.w, a4.w);
    }
    part4[eh * 32 + oq] = a4;
  }
  __syncthreads();
  if (t < 128) {
    float s = 0.f;
#pragma unroll
    for (int e8 = 0; e8 < 8; ++e8) s += ((const float*)&part4[e8 * 32 + (t >> 2)])[t & 3];
    buf[t] = bv[t] + s;
  }
  __syncthreads();

  {
    float4 a4 = {0.f, 0.f, 0.f, 0.f};
#pragma unroll 4
    for (int e = eh * 16; e < eh * 16 + 16; ++e) {
      const float4 wv = *(const float4*)(Wo + e * EE + oq * 4);
      const float xx = buf[e];
      a4.x = fmaf(xx, wv.x, a4.x); a4.y = fmaf(xx, wv.y, a4.y);
      a4.z = fmaf(xx, wv.z, a4.z); a4.w = fmaf(xx, wv.w, a4.w);
    }
    part4[eh * 32 + oq] = a4;
  }
  __syncthreads();
  if (t < 128) {
    float s = 0.f;
#pragma unroll
    for (int e8 = 0; e8 < 8; ++e8) s += ((const float*)&part4[e8 * 32 + (t >> 2)])[t & 3];
    ctxo[t] = bo[t] + s;
  }
  __syncthreads();

  if (t < 128) red[t] = ctxo[t];
  __syncthreads();
  for (int s = 64; s > 0; s >>= 1) { if (t < s) red[t] += red[t + s]; __syncthreads(); }
  const float mu = red[0] / EE;
  __syncthreads();
  if (t < 128) red[t] = (ctxo[t] - mu) * (ctxo[t] - mu);
  __syncthreads();
  for (int s = 64; s > 0; s >>= 1) { if (t < s) red[t] += red[t + s]; __syncthreads(); }
  const float rstd = rsqrtf(red[0] / EE + 1e-5f);
  __syncthreads();
  if (t < 128) buf[t] = (ctxo[t] - mu) * rstd * ln_g[t] + ln_b[t];
  __syncthreads();

  {
    float4 a4 = {0.f, 0.f, 0.f, 0.f};
#pragma unroll 4
    for (int e = eh * 16; e < eh * 16 + 16; ++e) {
      const float4 wv = *(const float4*)(Wp + e * EE + oq * 4);
      const float xx = buf[e];
      a4.x = fmaf(xx, wv.x, a4.x); a4.y = fmaf(xx, wv.y, a4.y);
      a4.z = fmaf(xx, wv.z, a4.z); a4.w = fmaf(xx, wv.w, a4.w);
    }
    part4[eh * 32 + oq] = a4;
  }
  __syncthreads();
  if (t < 128) {
    float s = 0.f;
#pragma unroll
    for (int e8 = 0; e8 < 8; ++e8) s += ((const float*)&part4[e8 * 32 + (t >> 2)])[t & 3];
    lg_s[t] = bp[t] + s;
  }
  __syncthreads();

  const float4 lg = *(const float4*)(lg_s + l * 4);
  const bool av = all_visited[b] != 0;
  const int pv = prev_node[b];
  const float direct = av ? ew[((size_t)b * NN + pv) * NN] : 1.f;
  const float sbv = sb_p[0], rpv = rp_p[0];
#pragma unroll
  for (int i = 0; i < 16; ++i) {
    const int nl = i * 8 + g;
    if (nl < 125) {
      const int n = nb + nl;
      const float4 a = pref[i];
      float d = a.x * lg.x + a.y * lg.y + a.z * lg.z + a.w * lg.w;
#pragma unroll
      for (int k = 16; k >= 1; k >>= 1) d += __shfl_xor(d, k, 32);
      if (l == 0) {
        float sc = d;
        if (!av) {
          if (visited[b * NN + n] != 0) sc = rpv;
        } else {
          const float via = ew[((size_t)b * NN + pv) * NN + n] + ew[((size_t)b * NN + n) * NN];
          if (via < direct) sc += sbv * (direct - via) / direct;
        }
        out[b * NN + n] = sc;
      }
    }
  }
}

extern "C" void kernel_launch(void* const* d_in, const int* in_sizes, int n_in,
                              void* d_out, int out_size, void* d_ws, size_t ws_size,
                              hipStream_t stream) {
  const float* ds   = (const float*)d_in[0];
  const float* ne   = (const float*)d_in[1];
  const int*   mask = (const int*)d_in[2];
  const float* ew   = (const float*)d_in[3];
  const int*   visited = (const int*)d_in[4];
  const int*   prev = (const int*)d_in[5];
  const int*   allv = (const int*)d_in[6];
  const float* Wq = (const float*)d_in[7];
  const float* bq = (const float*)d_in[8];
  const float* Wk = (const float*)d_in[9];
  const float* bk = (const float*)d_in[10];
  const float* Wv = (const float*)d_in[11];
  const float* bv = (const float*)d_in[12];
  const float* Wo = (const float*)d_in[13];
  const float* bo = (const float*)d_in[14];
  const float* Wp = (const float*)d_in[15];
  const float* bp = (const float*)d_in[16];
  const float* ln_g = (const float*)d_in[17];
  const float* ln_b = (const float*)d_in[18];
  const float* sb = (const float*)d_in[19];
  const float* rp = (const float*)d_in[20];
  float* out = (float*)d_out;
  char* ws = (char*)d_ws;

  short* pctx = (short*)ws;
  float* pm   = (float*)(ws + 2097152);
  float* ps   = (float*)(ws + 2129920);

  k_fused<<<dim3(16, BB), 256, 0, stream>>>(ds, ne, mask, Wq, bq, Wk, bk, pctx, pm, ps);
  k_head_scores<<<dim3(16, BB), 256, 0, stream>>>(ne, pctx, pm, ps, Wv, bv, Wo, bo, Wp, bp,
                                                  ln_g, ln_b, visited, prev, allv, ew, sb, rp, out);
}